// Round 3
// baseline (272.519 us; speedup 1.0000x reference)
//
#include <hip/hip_runtime.h>

typedef _Float16 h16;
typedef h16 h8_t __attribute__((ext_vector_type(8)));
typedef h16 h4_t __attribute__((ext_vector_type(4)));
typedef float f4_t __attribute__((ext_vector_type(4)));
typedef unsigned int u32;
typedef u32 u32a __attribute__((may_alias));
typedef unsigned int u4a __attribute__((ext_vector_type(4), may_alias));

#define LOG2E 1.4426950408889634f
// (1/sqrt(32)) * log2(e)  -- folded into q columns of w_qkv^T
#define QSCALE 0.25505998f
#define VT_LD 520

// workspace byte offsets (single-batch Q/K/VT, reused across b)
#define OFF_BIAS 0u
#define OFF_WQKV 524288u
#define OFF_WOUT 917504u
#define OFF_Q    1048576u
#define OFF_K    17825792u
#define OFF_VT   34603008u
// total 51,642,368 bytes (49.25 MiB)

static __device__ __forceinline__ u32 pkrtz(float a, float b) {
    return __builtin_bit_cast(u32, __builtin_amdgcn_cvt_pkrtz(a, b));
}

// ---------------- K0: precompute bias (log2e-scaled), w_qkv^T, w_out^T ----------------
__global__ __launch_bounds__(256) void k0_prep(const float* __restrict__ wqkv,
                                               const float* __restrict__ pos,
                                               const float* __restrict__ wout,
                                               h16* __restrict__ bias,
                                               h16* __restrict__ wT,
                                               h16* __restrict__ wToT)
{
    const int bid = blockIdx.x;
    const int e = bid * 256 + threadIdx.x;
    if (bid < 1024) {
        // bias[i][j] = pos[cj - ci + 7] * log2e  (i = query token, j = key token)
        int i = e >> 9, j = e & 511;
        int ix = i >> 6, iy = (i >> 3) & 7, iz = i & 7;
        int jx = j >> 6, jy = (j >> 3) & 7, jz = j & 7;
        int r0 = jx - ix + 7, r1 = jy - iy + 7, r2 = jz - iz + 7;
        float v = pos[(r0 * 15 + r1) * 15 + r2] * LOG2E;
        bias[i * 512 + j] = (h16)v;
    } else if (bid < 1792) {
        int t = e - 1024 * 256;
        int n = t >> 8, k = t & 255;
        float v = wqkv[k * 768 + n];
        if (n < 256) v *= QSCALE;          // scale the q channels
        wT[n * 256 + k] = (h16)v;
    } else {
        int t = e - 1792 * 256;
        int n = t >> 8, k = t & 255;
        wToT[n * 256 + k] = (h16)wout[k * 256 + n];
    }
}

// ---------------- K1: QKV projection for ONE batch, fused roll + window reorder ----------------
// block = 768 threads (12 waves), one block per 64-token tile (one ih-slab of one window)
__global__ __launch_bounds__(768) void k1_qkv(const float* __restrict__ x,  // batch base
                                              const h16* __restrict__ wT,
                                              h16* __restrict__ Qo,
                                              h16* __restrict__ Ko,
                                              h16* __restrict__ Vt)
{
    __shared__ __align__(16) h16 xs[64 * 256];   // 32KB fp16 x-tile, [tok][ch], 16B-granule XOR swizzle
    const int tid = threadIdx.x;
    const int tile = blockIdx.x;                  // w*8 + st
    const int st = tile & 7, w = tile >> 3;
    const int wh = w >> 4, ww = (w >> 2) & 3, wd = w & 3;
    const int Xs = (wh * 8 + st + 4) & 31;        // roll(-4): window frame -> original frame is +4 mod 32

    for (int i = tid; i < 4096; i += 768) {       // 64 rows x 64 16B-segments (f32)
        int row = i >> 6, seg = i & 63;
        int iw = row >> 3, id = row & 7;
        int Y = (ww * 8 + iw + 4) & 31, Z = (wd * 8 + id + 4) & 31;
        const float* xp = x + ((Xs * 32 + Y) * 32 + Z) * 256 + seg * 4;
        f4_t v = *(const f4_t*)xp;
        uint2 tmp;
        tmp.x = pkrtz(v[0], v[1]);
        tmp.y = pkrtz(v[2], v[3]);
        *(uint2*)((char*)xs + row * 512 + (((u32)(seg * 8)) ^ ((u32)(row & 7) << 4))) = tmp;
    }
    __syncthreads();

    const int wv = tid >> 6, lane = tid & 63;
    const int c = lane & 15, hi = lane >> 4;
    f4_t acc[4][4];
#pragma unroll
    for (int i = 0; i < 4; ++i)
#pragma unroll
        for (int j = 0; j < 4; ++j) { f4_t z = {0.f, 0.f, 0.f, 0.f}; acc[i][j] = z; }

#pragma unroll 2
    for (int ks = 0; ks < 8; ++ks) {
        h8_t a[4], bfr[4];
#pragma unroll
        for (int rf = 0; rf < 4; ++rf)
            a[rf] = *(const h8_t*)(wT + (wv * 64 + rf * 16 + c) * 256 + ks * 32 + hi * 8);
#pragma unroll
        for (int cf = 0; cf < 4; ++cf) {
            int tok = cf * 16 + c;
            bfr[cf] = *(const h8_t*)((const char*)xs + tok * 512 +
                                     (((u32)(ks * 64 + hi * 16)) ^ ((u32)(tok & 7) << 4)));
        }
#pragma unroll
        for (int rf = 0; rf < 4; ++rf)
#pragma unroll
            for (int cf = 0; cf < 4; ++cf)
                acc[rf][cf] = __builtin_amdgcn_mfma_f32_16x16x32_f16(a[rf], bfr[cf], acc[rf][cf], 0, 0, 0);
    }

    const int wbh = w * 8;
#pragma unroll
    for (int rf = 0; rf < 4; ++rf) {
        const int ch = wv * 64 + rf * 16 + hi * 4;   // C rows = hi*4+reg
        const int sel = ch >> 8;                      // 0=q 1=k 2=v (uniform per wave)
        const int ch2 = ch & 255, hh = ch2 >> 5, d = ch2 & 31;
#pragma unroll
        for (int cf = 0; cf < 4; ++cf) {
            const int t = st * 64 + cf * 16 + c;
            f4_t v = acc[rf][cf];
            if (sel == 2) {
                // V stored transposed: Vt[w,h][d][t]
                h16* vp = Vt + (wbh + hh) * (32 * VT_LD) + d * VT_LD + t;
                vp[0] = (h16)v[0];
                vp[VT_LD] = (h16)v[1];
                vp[2 * VT_LD] = (h16)v[2];
                vp[3 * VT_LD] = (h16)v[3];
            } else {
                h16* qp = (sel ? Ko : Qo) + ((wbh + hh) * 512 + t) * 32 + d;
                uint2 sv;
                sv.x = pkrtz(v[0], v[1]);
                sv.y = pkrtz(v[2], v[3]);
                *(uint2*)qp = sv;
            }
        }
    }
}

// ---------------- KA: fused flash attention + output projection, ONE batch ----------------
// block = (w, st): 64 q-tokens, 8 waves = 8 heads. Wave does flash attn for its head
// (swapped QK^T so softmax reduce = 2 shfl_xor; P repacked via per-wave LDS buffer),
// result staged in LDS, then all 8 waves project 64 tok x 256 ch and scatter w/ roll-back.
__global__ __launch_bounds__(512) void ka_fused(const h16* __restrict__ Qb_,
                                                const h16* __restrict__ Kb_,
                                                const h16* __restrict__ Vt_,
                                                const h16* __restrict__ Bi,
                                                const h16* __restrict__ wToT,
                                                const float* __restrict__ bout,
                                                float* __restrict__ out)   // batch base
{
    __shared__ __align__(16) h16 as[64 * 264];     // attn result [tok][ch], pad 264
    __shared__ __align__(16) u32 plds[8][64 * 20]; // per-wave P tile [q][kt] as u32 pairs, row=20 dwords
    const int tid = threadIdx.x;
    const int lane = tid & 63, hh = tid >> 6;
    const int c = lane & 15, hi = lane >> 4;
    const int blk = blockIdx.x;                    // w*8 + st
    const int st = blk & 7, w = blk >> 3;
    const int qbase = st * 64;
    const int base = w * 8 + hh;
    const h16* Qp = Qb_ + base * (512 * 32);
    const h16* Kp = Kb_ + base * (512 * 32);
    const h16* Vp = Vt_ + base * (32 * VT_LD);
    u32a* pw = (u32a*)&plds[hh][0];

    h8_t qf[4];
#pragma unroll
    for (int cf = 0; cf < 4; ++cf)
        qf[cf] = *(const h8_t*)(Qp + (qbase + cf * 16 + c) * 32 + hi * 8);

    f4_t acc[2][4];
#pragma unroll
    for (int i = 0; i < 2; ++i)
#pragma unroll
        for (int j = 0; j < 4; ++j) { f4_t z = {0.f, 0.f, 0.f, 0.f}; acc[i][j] = z; }
    float m[4] = {-3e38f, -3e38f, -3e38f, -3e38f};
    float l[4] = {0.f, 0.f, 0.f, 0.f};

    for (int kc = 0; kc < 16; ++kc) {
        const int kt0 = kc * 32;
        h8_t kf[2], vf[2];
        kf[0] = *(const h8_t*)(Kp + (kt0 + c) * 32 + hi * 8);
        kf[1] = *(const h8_t*)(Kp + (kt0 + 16 + c) * 32 + hi * 8);
        vf[0] = *(const h8_t*)(Vp + c * VT_LD + kt0 + hi * 8);
        vf[1] = *(const h8_t*)(Vp + (16 + c) * VT_LD + kt0 + hi * 8);

        f4_t s[2][4];
#pragma unroll
        for (int rf = 0; rf < 2; ++rf)
#pragma unroll
            for (int cf = 0; cf < 4; ++cf) {
                // bias as the MFMA C operand (already in log2e domain)
                h4_t bv = *(const h4_t*)(Bi + (qbase + cf * 16 + c) * 512 + kt0 + rf * 16 + hi * 4);
                f4_t si;
                si[0] = (float)bv[0]; si[1] = (float)bv[1];
                si[2] = (float)bv[2]; si[3] = (float)bv[3];
                s[rf][cf] = __builtin_amdgcn_mfma_f32_16x16x32_f16(kf[rf], qf[cf], si, 0, 0, 0);
            }

#pragma unroll
        for (int cf = 0; cf < 4; ++cf) {
            f4_t s0 = s[0][cf], s1 = s[1][cf];
            float cm = fmaxf(fmaxf(fmaxf(s0[0], s0[1]), fmaxf(s0[2], s0[3])),
                             fmaxf(fmaxf(s1[0], s1[1]), fmaxf(s1[2], s1[3])));
            cm = fmaxf(cm, __shfl_xor(cm, 16));
            cm = fmaxf(cm, __shfl_xor(cm, 32));
            float mn = fmaxf(m[cf], cm);
            float alpha = __builtin_amdgcn_exp2f(m[cf] - mn);
            m[cf] = mn;
            float p0[4], p1[4];
            float rs = 0.f;
#pragma unroll
            for (int r = 0; r < 4; ++r) { p0[r] = __builtin_amdgcn_exp2f(s0[r] - mn); rs += p0[r]; }
#pragma unroll
            for (int r = 0; r < 4; ++r) { p1[r] = __builtin_amdgcn_exp2f(s1[r] - mn); rs += p1[r]; }
            rs += __shfl_xor(rs, 16);
            rs += __shfl_xor(rs, 32);
            l[cf] = l[cf] * alpha + rs;
#pragma unroll
            for (int dd = 0; dd < 2; ++dd) {
                f4_t a = acc[dd][cf];
                a[0] *= alpha; a[1] *= alpha; a[2] *= alpha; a[3] *= alpha;
                acc[dd][cf] = a;
            }
            // P repack via per-wave LDS: write P[q][kt] (q row = cf*16+c, 20 dwords/row)
            const int prow = (cf * 16 + c) * 20;
            pw[prow + hi * 2]     = pkrtz(p0[0], p0[1]);   // kt = hi*4, hi*4+1
            pw[prow + hi * 2 + 1] = pkrtz(p0[2], p0[3]);   // kt = hi*4+2, +3
            pw[prow + 8 + hi * 2]     = pkrtz(p1[0], p1[1]);  // kt = 16+hi*4 ...
            pw[prow + 8 + hi * 2 + 1] = pkrtz(p1[2], p1[3]);
            // read back as B-frag: kt = hi*8 .. hi*8+7 for q = cf*16+c
            u4a pbu = *(const u4a*)(pw + prow + hi * 4);
            h8_t pb = __builtin_bit_cast(h8_t, pbu);
#pragma unroll
            for (int dd = 0; dd < 2; ++dd)
                acc[dd][cf] = __builtin_amdgcn_mfma_f32_16x16x32_f16(vf[dd], pb, acc[dd][cf], 0, 0, 0);
        }
    }

    // normalize and stage attention result in LDS: as[tl][hh*32 + d]
#pragma unroll
    for (int cf = 0; cf < 4; ++cf) {
        float rl = __builtin_amdgcn_rcpf(l[cf]);
        const int tl = cf * 16 + c;
#pragma unroll
        for (int dd = 0; dd < 2; ++dd) {
            f4_t v = acc[dd][cf];
            uint2 sv;
            sv.x = pkrtz(v[0] * rl, v[1] * rl);
            sv.y = pkrtz(v[2] * rl, v[3] * rl);
            *(uint2*)(as + tl * 264 + hh * 32 + dd * 16 + hi * 4) = sv;
        }
    }
    __syncthreads();

    // ---- output projection: wave hh handles output channels [hh*32, hh*32+32) ----
    f4_t pacc[2][4];
#pragma unroll
    for (int i = 0; i < 2; ++i)
#pragma unroll
        for (int j = 0; j < 4; ++j) { f4_t z = {0.f, 0.f, 0.f, 0.f}; pacc[i][j] = z; }

#pragma unroll 2
    for (int ks = 0; ks < 8; ++ks) {
        h8_t a2[2], b2[4];
#pragma unroll
        for (int rf = 0; rf < 2; ++rf)
            a2[rf] = *(const h8_t*)(wToT + (hh * 32 + rf * 16 + c) * 256 + ks * 32 + hi * 8);
#pragma unroll
        for (int cf = 0; cf < 4; ++cf)
            b2[cf] = *(const h8_t*)(as + (cf * 16 + c) * 264 + ks * 32 + hi * 8);
#pragma unroll
        for (int rf = 0; rf < 2; ++rf)
#pragma unroll
            for (int cf = 0; cf < 4; ++cf)
                pacc[rf][cf] = __builtin_amdgcn_mfma_f32_16x16x32_f16(a2[rf], b2[cf], pacc[rf][cf], 0, 0, 0);
    }

    const int wh = w >> 4, ww = (w >> 2) & 3, wd = w & 3;
    const int X = (wh * 8 + st + 4) & 31;
#pragma unroll
    for (int cf = 0; cf < 4; ++cf) {
        const int tl = cf * 16 + c;
        const int Y = (ww * 8 + (tl >> 3) + 4) & 31, Z = (wd * 8 + (tl & 7) + 4) & 31;
        float* op = out + ((X * 32 + Y) * 32 + Z) * 256;
#pragma unroll
        for (int rf = 0; rf < 2; ++rf) {
            const int co = hh * 32 + rf * 16 + hi * 4;
            f4_t bo = *(const f4_t*)(bout + co);
            f4_t v = pacc[rf][cf];
            v[0] += bo[0]; v[1] += bo[1]; v[2] += bo[2]; v[3] += bo[3];
            *(f4_t*)(op + co) = v;
        }
    }
}

extern "C" void kernel_launch(void* const* d_in, const int* in_sizes, int n_in,
                              void* d_out, int out_size, void* d_ws, size_t ws_size,
                              hipStream_t stream)
{
    (void)in_sizes; (void)n_in; (void)out_size; (void)ws_size;
    const float* x    = (const float*)d_in[0];
    const float* wqkv = (const float*)d_in[1];
    const float* pos  = (const float*)d_in[2];
    const float* wout = (const float*)d_in[3];
    const float* bout = (const float*)d_in[4];
    float* out = (float*)d_out;
    char* ws = (char*)d_ws;

    h16* bias = (h16*)(ws + OFF_BIAS);
    h16* wT   = (h16*)(ws + OFF_WQKV);
    h16* wToT = (h16*)(ws + OFF_WOUT);
    h16* Q    = (h16*)(ws + OFF_Q);
    h16* K    = (h16*)(ws + OFF_K);
    h16* VT   = (h16*)(ws + OFF_VT);

    const size_t BSTR = 32768u * 256u;   // per-batch elements of x / out

    k0_prep<<<2048, 256, 0, stream>>>(wqkv, pos, wout, bias, wT, wToT);
    for (int b = 0; b < 2; ++b) {
        k1_qkv<<<512, 768, 0, stream>>>(x + b * BSTR, wT, Q, K, VT);
        ka_fused<<<512, 512, 0, stream>>>(Q, K, VT, bias, wToT, bout, out + b * BSTR);
    }
}